// Round 4
// baseline (603.384 us; speedup 1.0000x reference)
//
#include <hip/hip_runtime.h>
#include <hip/hip_cooperative_groups.h>
#include <climits>

namespace cg = cooperative_groups;

#define B_ 2
#define V_ 4
#define H_ 120
#define W_ 160
#define C_ 96
#define NVOX 200000
#define GRID_ 128
#define NSTEPS 156
#define NRAYS (B_*V_*H_*W_)       // 153600
#define NB1 ((NVOX + 255) / 256)  // 782 virtual blocks over voxels
#define NB5 (NRAYS / 256)         // 600 virtual blocks over rays
#define CHUNK 32                  // sorted-list entries per wave in chunk_reduce
#define NCHUNK ((NRAYS + CHUNK - 1) / CHUNK)
#define NWAVE_MARCH (NRAYS / 16)  // 9600 marching waves (16 rays/wave, PARR=4)
#define MASKW (B_ * GRID_ * GRID_ * GRID_ / 64)   // 65536 u64 words
#define OUTQ ((NVOX * (C_ + 1)) / 4)              // 4,850,000 float4s in d_out

// ---------------- run flush: middle runs need no cnt/segstart ---------------
__device__ __forceinline__ void flush_run2(int t, int ks, int ke, int n,
                                           float ax, float ay, int lane,
                                           const int* __restrict__ segstart,
                                           const int* __restrict__ cnt,
                                           float* __restrict__ out,
                                           float* __restrict__ cnt_out) {
    int c;
    bool complete;
    if (ks > 0 && ke < n) {          // middle run: whole segment inside chunk
        c = ke - ks;
        complete = true;
    } else {
        c = cnt[t];
        int s = segstart[t];
        complete = (s / CHUNK) == ((s + c - 1) / CHUNK);
    }
    if (complete) {
        float denom = (float)c + 0.0001f;
        if (lane < 48) {
            float2 wv; wv.x = ax / denom; wv.y = ay / denom;
            ((float2*)(out + (size_t)t * C_))[lane] = wv;
        }
        if (lane == 0) cnt_out[t] = (float)c;
    } else if (lane < 48) {          // crossing: accumulate into zeroed row
        unsafeAtomicAdd(out + (size_t)t * C_ + 2 * lane,     ax);
        unsafeAtomicAdd(out + (size_t)t * C_ + 2 * lane + 1, ay);
    }
}

// ============================================================================
// Fused cooperative kernel (round-3 was a compile typo: MultiProcessor ->
// Multiprocessor; logic unchanged). Round-2 failure post-mortem: hard-coded
// 1024-block cooperative launch was rejected by runtime validation (output
// stayed all zeros -> absmax == max ref cnt == 1600). Fixes:
//   (a) grid size comes from the runtime's OWN occupancy query (host, cached);
//   (b) every phase is grid-stride correct at ANY grid size;
//   (c) launch error checked; verified multi-kernel fallback if it fails;
//   (d) ws zero region written through its own (non-aliased) pointers.
// ============================================================================
__global__ __launch_bounds__(256, 4) void mega_kernel(
    const float* __restrict__ feats,
    const int* __restrict__ coords,
    const float* __restrict__ vm,
    const float* __restrict__ intr,
    int* sneg,
    int* cnt,
    unsigned long long* mask,
    int* gtotal,
    int* wlcount,
    int* __restrict__ tgt,
    int* __restrict__ segstart,
    int* __restrict__ cursor,
    int* __restrict__ wl,
    int2* __restrict__ sorted_rt,
    int* __restrict__ occ,
    float* __restrict__ out,
    float* __restrict__ cnt_out)
{
    __shared__ int smax[B_ * 3];
    __shared__ int wtot[4];
    const int tid      = threadIdx.x;
    const int lane     = tid & 63;
    const int nthreads = gridDim.x * 256;
    const int gthread  = blockIdx.x * 256 + tid;
    const int nwaves   = gridDim.x * 4;
    const int gwave    = blockIdx.x * 4 + (tid >> 6);

    // ---- P0: zero ws regions (each via its own pointer: no aliasing UB) ----
    for (int i = gthread; i < NVOX; i += nthreads) cnt[i] = 0;
    for (int i = gthread; i < MASKW; i += nthreads) mask[i] = 0ull;
    if (gthread < B_ * 3) sneg[gthread] = 0;
    if (gthread == 0) { *gtotal = 0; *wlcount = 0; }
    cg::this_grid().sync();

    // ---- P1: per-batch min via atomicMax(127-coord) ------------------------
    if (tid < B_ * 3) smax[tid] = 0;
    __syncthreads();
    for (int i = gthread; i < NVOX; i += nthreads) {
        int b = coords[i * 4 + 0];
        atomicMax(&smax[b * 3 + 0], 127 - coords[i * 4 + 1]);
        atomicMax(&smax[b * 3 + 1], 127 - coords[i * 4 + 2]);
        atomicMax(&smax[b * 3 + 2], 127 - coords[i * 4 + 3]);
    }
    __syncthreads();
    if (tid < B_ * 3 && smax[tid] > 0) atomicMax(&sneg[tid], smax[tid]);
    cg::this_grid().sync();

    // ---- P2: occ id grid (last-dup wins) + 64-bit occupancy bitmask --------
    // occ NOT pre-initialized (mask gates which cells march reads; duplicate
    // cells get atomicMax so the max ray-id wins, matching .set last-dup).
    for (int i = gthread; i < NVOX; i += nthreads) {
        int b = coords[i * 4 + 0];
        int x = coords[i * 4 + 1] - (127 - sneg[b * 3 + 0]);
        int y = coords[i * 4 + 2] - (127 - sneg[b * 3 + 1]);
        int z = coords[i * 4 + 3] - (127 - sneg[b * 3 + 2]);
        int idx = ((b * GRID_ + z) * GRID_ + y) * GRID_ + x;
        atomicMax(&occ[idx], i);
        atomicOr(&mask[idx >> 6], 1ull << (idx & 63));
    }
    cg::this_grid().sync();

    // ---- P3: step-parallel march + wave-aggregated cnt + d_out zeroing -----
    {
        const int p   = lane & 15;
        const int sub = lane >> 4;
        const float fx = intr[0], fy = intr[1], cx = intr[2], cy = intr[3];
        const int MISS = 0x7FFFFFFF;
        for (int wv = gwave; wv < NWAVE_MARCH; wv += nwaves) {
            int r = wv * 16 + p;
            int w = r % W_;
            int h = (r / W_) % H_;
            int v = (r / (W_ * H_)) % V_;
            int b = r / (W_ * H_ * V_);
            const float* M = vm + (size_t)(b * V_ + v) * 16;
            float dx = ((float)w + 0.5f - cx) / fx;
            float dy = ((float)h + 0.5f - cy) / fy;
            float d0 = M[0] * dx + M[1] * dy + M[2];
            float d1 = M[4] * dx + M[5] * dy + M[6];
            float d2 = M[8] * dx + M[9] * dy + M[10];
            float t0 = M[3]  - (float)(127 - sneg[b * 3 + 0]);
            float t1 = M[7]  - (float)(127 - sneg[b * 3 + 1]);
            float t2 = M[11] - (float)(127 - sneg[b * 3 + 2]);
            const int vbase = b * GRID_ * GRID_ * GRID_;
            int beststep = MISS;
            for (int w0 = 0; w0 < NSTEPS; w0 += 32) {
                int lin[8]; bool ok[8];
#pragma unroll
                for (int j = 0; j < 8; ++j) {
                    int st = w0 + sub * 8 + j;
                    float t = 2.0f + 0.5f * (float)st;
                    float pwx = d0 * t + t0;
                    float pwy = d1 * t + t1;
                    float pwz = d2 * t + t2;
                    int ix = (int)floorf(pwx);
                    int iy = (int)floorf(pwy);
                    int iz = (int)floorf(pwz);
                    ok[j] = ((unsigned)ix < (unsigned)GRID_) &
                            ((unsigned)iy < (unsigned)GRID_) &
                            ((unsigned)iz < (unsigned)GRID_) & (st < NSTEPS);
                    int cix = min(max(ix, 0), GRID_ - 1);
                    int ciy = min(max(iy, 0), GRID_ - 1);
                    int ciz = min(max(iz, 0), GRID_ - 1);
                    lin[j] = vbase + (ciz << 14) + (ciy << 7) + cix;
                }
                unsigned long long u[8];
                bool same[8];
                same[0] = false;
#pragma unroll
                for (int j = 1; j < 8; ++j) same[j] = ((lin[j] >> 6) == (lin[j - 1] >> 6));
#pragma unroll
                for (int j = 0; j < 8; ++j)
                    if (!same[j]) u[j] = mask[lin[j] >> 6];
#pragma unroll
                for (int j = 1; j < 8; ++j)
                    if (same[j]) u[j] = u[j - 1];
                int local = MISS;
#pragma unroll
                for (int j = 0; j < 8; ++j) {
                    int st = w0 + sub * 8 + j;
                    if (ok[j] && ((u[j] >> (lin[j] & 63)) & 1ull)) local = min(local, st);
                }
                local = min(local, __shfl_xor(local, 16));
                local = min(local, __shfl_xor(local, 32));
                if (local != MISS) { beststep = local; break; }
            }
            int res = -1;
            if (sub == 0) {
                if (beststep != MISS) {
                    float t = 2.0f + 0.5f * (float)beststep;
                    int ix = (int)floorf(d0 * t + t0);
                    int iy = (int)floorf(d1 * t + t1);
                    int iz = (int)floorf(d2 * t + t2);
                    res = occ[vbase + (iz << 14) + (iy << 7) + ix];
                }
                tgt[r] = res;
            }
            // wave-aggregated histogram: one atomic per equal-target run
            bool active = (sub == 0) && (res >= 0);
            int prevres = __shfl_up(res, 1);
            bool head = active && (p == 0 || prevres != res);
            bool boundary = head || !active;
            unsigned long long bb = __ballot(boundary);
            if (head) {
                unsigned long long above = bb & ~((2ull << lane) - 1);
                int next = above ? (__ffsll((long long)above) - 1) : 64;
                atomicAdd(&cnt[res], next - lane);
            }
        }
        // d_out zero (77.6 MB) folded here: overlaps march's latency-bound
        // tail; needed before P6 (2 grid syncs downstream).
        float4 z4 = make_float4(0.f, 0.f, 0.f, 0.f);
        float4* o4 = (float4*)out;
        for (int i = gthread; i < OUTQ; i += nthreads) o4[i] = z4;
    }
    cg::this_grid().sync();

    // ---- P4: segment allocator + crossing worklist (block-strided) ---------
    for (int vb = blockIdx.x; vb < NB1; vb += gridDim.x) {
        int wid = tid >> 6;
        int i = vb * 256 + tid;
        int c = (i < NVOX) ? cnt[i] : 0;
        int x = c;
#pragma unroll
        for (int d = 1; d < 64; d <<= 1) {
            int y = __shfl_up(x, d);
            if (lane >= d) x += y;
        }
        if (lane == 63) wtot[wid] = x;
        __syncthreads();
        if (tid == 0) {
            int s0 = wtot[0], s1 = wtot[1], s2 = wtot[2], s3 = wtot[3];
            int base = atomicAdd(gtotal, s0 + s1 + s2 + s3);
            wtot[0] = base;
            wtot[1] = base + s0;
            wtot[2] = base + s0 + s1;
            wtot[3] = base + s0 + s1 + s2;
        }
        __syncthreads();
        if (i < NVOX) {
            int s = wtot[wid] + (x - c);
            segstart[i] = s;
            cursor[i]   = s;
            if (c > 0 && (s / CHUNK) != ((s + c - 1) / CHUNK)) {
                int pidx = atomicAdd(wlcount, 1);
                wl[pidx] = i;
            }
        }
        __syncthreads();   // protect wtot reuse across vb iterations
    }
    cg::this_grid().sync();

    // ---- P5: wave-aggregated bucket scatter (block-strided) ----------------
    for (int vb = blockIdx.x; vb < NB5; vb += gridDim.x) {
        int r = vb * 256 + tid;
        int t = tgt[r];
        bool active = t >= 0;
        int prev = __shfl_up(t, 1);
        bool head = active && (lane == 0 || prev != t);
        bool boundary = head || !active;
        unsigned long long bb = __ballot(boundary);
        unsigned long long below = bb & ((2ull << lane) - 1);
        int headpos = 63 - __clzll(below | 1ull);
        int base = 0;
        if (head) {
            unsigned long long above = bb & ~((2ull << lane) - 1);
            int next = above ? (__ffsll((long long)above) - 1) : 64;
            int runlen = next - lane;
            base = atomicAdd(&cursor[t], runlen);
        }
        base = __shfl(base, headpos);
        if (active) sorted_rt[base + (lane - headpos)] = make_int2(r, t);
    }
    cg::this_grid().sync();

    // ---- P6: chunked segmented reduce (8-deep pipeline, wave-strided) ------
    {
        int total = gtotal[0];
        for (int wv = gwave; wv * CHUNK < total; wv += nwaves) {
            int a = wv * CHUNK;
            int n = min(CHUNK, total - a);
            int myr = 0, myt = 0;
            if (lane < n) { int2 e = sorted_rt[a + lane]; myr = e.x; myt = e.y; }
            float ax = 0.0f, ay = 0.0f;
            int cur = -1, run_start = 0;
            for (int k0 = 0; k0 < n; k0 += 8) {
                float2 vbuf[8]; int tt[8];
#pragma unroll
                for (int j = 0; j < 8; ++j) {
                    int k = k0 + j;
                    int rr = __shfl(myr, k);
                    tt[j]  = __shfl(myt, k);
                    vbuf[j] = make_float2(0.0f, 0.0f);
                    if (k < n && lane < 48)
                        vbuf[j] = ((const float2*)(feats + (size_t)rr * C_))[lane];
                }
#pragma unroll
                for (int j = 0; j < 8; ++j) {
                    int k = k0 + j;
                    if (k >= n) break;
                    if (tt[j] != cur) {
                        if (cur >= 0)
                            flush_run2(cur, run_start, k, n, ax, ay, lane, segstart, cnt, out, cnt_out);
                        cur = tt[j]; run_start = k; ax = 0.0f; ay = 0.0f;
                    }
                    ax += vbuf[j].x; ay += vbuf[j].y;
                }
            }
            flush_run2(cur, run_start, n, n, ax, ay, lane, segstart, cnt, out, cnt_out);
        }
    }
    cg::this_grid().sync();

    // ---- P7: finalize crossing voxels from worklist ------------------------
    {
        int wlc = wlcount[0];
        for (int idx = gwave; idx < wlc; idx += nwaves) {
            int vox = wl[idx];
            int c = cnt[vox];
            float denom = (float)c + 0.0001f;
            if (lane < 48) {
                float2* o = (float2*)(out + (size_t)vox * C_);
                float2 x = o[lane];
                x.x /= denom; x.y /= denom;
                o[lane] = x;
            }
            if (lane == 0) cnt_out[vox] = (float)c;
        }
    }
}

// ======================= FALLBACK: verified multi-kernel path ================
__global__ void shift_kernel(const int* __restrict__ coords, int* __restrict__ sneg) {
    __shared__ int smax[B_ * 3];
    int t = threadIdx.x;
    if (t < B_ * 3) smax[t] = 0;
    __syncthreads();
    int i = blockIdx.x * blockDim.x + t;
    if (i < NVOX) {
        int b = coords[i * 4 + 0];
        atomicMax(&smax[b * 3 + 0], 127 - coords[i * 4 + 1]);
        atomicMax(&smax[b * 3 + 1], 127 - coords[i * 4 + 2]);
        atomicMax(&smax[b * 3 + 2], 127 - coords[i * 4 + 3]);
    }
    __syncthreads();
    if (t < B_ * 3 && smax[t] > 0) atomicMax(&sneg[t], smax[t]);
}

__global__ void occ_kernel(const int* __restrict__ coords,
                           const int* __restrict__ sneg,
                           int* __restrict__ occ,
                           unsigned long long* __restrict__ mask) {
    int i = blockIdx.x * blockDim.x + threadIdx.x;
    if (i >= NVOX) return;
    int b = coords[i * 4 + 0];
    int x = coords[i * 4 + 1] - (127 - sneg[b * 3 + 0]);
    int y = coords[i * 4 + 2] - (127 - sneg[b * 3 + 1]);
    int z = coords[i * 4 + 3] - (127 - sneg[b * 3 + 2]);
    int idx = ((b * GRID_ + z) * GRID_ + y) * GRID_ + x;
    atomicMax(&occ[idx], i);
    atomicOr(&mask[idx >> 6], 1ull << (idx & 63));
}

__global__ void march_kernel(const float* __restrict__ vm,
                             const float* __restrict__ intr,
                             const int* __restrict__ sneg,
                             const unsigned long long* __restrict__ mask,
                             const int* __restrict__ occ,
                             int* __restrict__ tgt,
                             int* __restrict__ cnt) {
    int gt   = blockIdx.x * blockDim.x + threadIdx.x;
    int lane = threadIdx.x & 63;
    int p    = lane & 15;
    int sub  = lane >> 4;
    int r    = ((gt >> 6) << 4) + p;
    if (r >= NRAYS) return;
    int w = r % W_;
    int h = (r / W_) % H_;
    int v = (r / (W_ * H_)) % V_;
    int b = r / (W_ * H_ * V_);
    const float* M = vm + (size_t)(b * V_ + v) * 16;
    float fx = intr[0], fy = intr[1], cx = intr[2], cy = intr[3];
    float dx = ((float)w + 0.5f - cx) / fx;
    float dy = ((float)h + 0.5f - cy) / fy;
    float d0 = M[0] * dx + M[1] * dy + M[2];
    float d1 = M[4] * dx + M[5] * dy + M[6];
    float d2 = M[8] * dx + M[9] * dy + M[10];
    float t0 = M[3]  - (float)(127 - sneg[b * 3 + 0]);
    float t1 = M[7]  - (float)(127 - sneg[b * 3 + 1]);
    float t2 = M[11] - (float)(127 - sneg[b * 3 + 2]);
    const int vbase = b * GRID_ * GRID_ * GRID_;
    const int MISS = 0x7FFFFFFF;
    int beststep = MISS;
    for (int w0 = 0; w0 < NSTEPS; w0 += 32) {
        int lin[8]; bool ok[8];
#pragma unroll
        for (int j = 0; j < 8; ++j) {
            int st = w0 + sub * 8 + j;
            float t = 2.0f + 0.5f * (float)st;
            float pwx = d0 * t + t0;
            float pwy = d1 * t + t1;
            float pwz = d2 * t + t2;
            int ix = (int)floorf(pwx);
            int iy = (int)floorf(pwy);
            int iz = (int)floorf(pwz);
            ok[j] = ((unsigned)ix < (unsigned)GRID_) &
                    ((unsigned)iy < (unsigned)GRID_) &
                    ((unsigned)iz < (unsigned)GRID_) & (st < NSTEPS);
            int cix = min(max(ix, 0), GRID_ - 1);
            int ciy = min(max(iy, 0), GRID_ - 1);
            int ciz = min(max(iz, 0), GRID_ - 1);
            lin[j] = vbase + (ciz << 14) + (ciy << 7) + cix;
        }
        unsigned long long u[8];
        bool same[8];
        same[0] = false;
#pragma unroll
        for (int j = 1; j < 8; ++j) same[j] = ((lin[j] >> 6) == (lin[j - 1] >> 6));
#pragma unroll
        for (int j = 0; j < 8; ++j)
            if (!same[j]) u[j] = mask[lin[j] >> 6];
#pragma unroll
        for (int j = 1; j < 8; ++j)
            if (same[j]) u[j] = u[j - 1];
        int local = MISS;
#pragma unroll
        for (int j = 0; j < 8; ++j) {
            int st = w0 + sub * 8 + j;
            if (ok[j] && ((u[j] >> (lin[j] & 63)) & 1ull)) local = min(local, st);
        }
        local = min(local, __shfl_xor(local, 16));
        local = min(local, __shfl_xor(local, 32));
        if (local != MISS) { beststep = local; break; }
    }
    int res = -1;
    if (sub == 0) {
        if (beststep != MISS) {
            float t = 2.0f + 0.5f * (float)beststep;
            int ix = (int)floorf(d0 * t + t0);
            int iy = (int)floorf(d1 * t + t1);
            int iz = (int)floorf(d2 * t + t2);
            res = occ[vbase + (iz << 14) + (iy << 7) + ix];
        }
        tgt[r] = res;
    }
    bool active = (sub == 0) && (res >= 0);
    int prevres = __shfl_up(res, 1);
    bool head = active && (p == 0 || prevres != res);
    bool boundary = head || !active;
    unsigned long long bb = __ballot(boundary);
    if (head) {
        unsigned long long above = bb & ~((2ull << lane) - 1);
        int next = above ? (__ffsll((long long)above) - 1) : 64;
        atomicAdd(&cnt[res], next - lane);
    }
}

__global__ void alloc_kernel(const int* __restrict__ cnt,
                             int* __restrict__ gtotal,
                             int* __restrict__ segstart,
                             int* __restrict__ cursor,
                             int* __restrict__ wl,
                             int* __restrict__ wlcount) {
    __shared__ int wtot[4];
    int tid  = threadIdx.x;
    int lane = tid & 63;
    int wid  = tid >> 6;
    int i = blockIdx.x * 256 + tid;
    int c = (i < NVOX) ? cnt[i] : 0;
    int x = c;
#pragma unroll
    for (int d = 1; d < 64; d <<= 1) {
        int y = __shfl_up(x, d);
        if (lane >= d) x += y;
    }
    if (lane == 63) wtot[wid] = x;
    __syncthreads();
    if (tid == 0) {
        int s0 = wtot[0], s1 = wtot[1], s2 = wtot[2], s3 = wtot[3];
        int base = atomicAdd(gtotal, s0 + s1 + s2 + s3);
        wtot[0] = base;
        wtot[1] = base + s0;
        wtot[2] = base + s0 + s1;
        wtot[3] = base + s0 + s1 + s2;
    }
    __syncthreads();
    if (i >= NVOX) return;
    int s = wtot[wid] + (x - c);
    segstart[i] = s;
    cursor[i]   = s;
    if (c > 0 && (s / CHUNK) != ((s + c - 1) / CHUNK)) {
        int pidx = atomicAdd(wlcount, 1);
        wl[pidx] = i;
    }
}

__global__ void order_kernel(const int* __restrict__ tgt,
                             int* __restrict__ cursor, int2* __restrict__ sorted_rt) {
    int r = blockIdx.x * blockDim.x + threadIdx.x;
    int lane = threadIdx.x & 63;
    int t = tgt[r];
    bool active = t >= 0;
    int prev = __shfl_up(t, 1);
    bool head = active && (lane == 0 || prev != t);
    bool boundary = head || !active;
    unsigned long long bb = __ballot(boundary);
    unsigned long long below = bb & ((2ull << lane) - 1);
    int headpos = 63 - __clzll(below | 1ull);
    int base = 0;
    if (head) {
        unsigned long long above = bb & ~((2ull << lane) - 1);
        int next = above ? (__ffsll((long long)above) - 1) : 64;
        int runlen = next - lane;
        base = atomicAdd(&cursor[t], runlen);
    }
    base = __shfl(base, headpos);
    if (active) sorted_rt[base + (lane - headpos)] = make_int2(r, t);
}

__global__ void chunk_reduce_kernel(const float* __restrict__ feats,
                                    const int2* __restrict__ sorted_rt,
                                    const int* __restrict__ segstart,
                                    const int* __restrict__ cnt,
                                    const int* __restrict__ total_p,
                                    float* __restrict__ out,
                                    float* __restrict__ cnt_out) {
    int wave = (blockIdx.x * blockDim.x + threadIdx.x) >> 6;
    int lane = threadIdx.x & 63;
    int total = total_p[0];
    int a = wave * CHUNK;
    if (a >= total) return;
    int n = min(CHUNK, total - a);
    int myr = 0, myt = 0;
    if (lane < n) { int2 e = sorted_rt[a + lane]; myr = e.x; myt = e.y; }
    float ax = 0.0f, ay = 0.0f;
    int cur = -1, run_start = 0;
    for (int k0 = 0; k0 < n; k0 += 8) {
        float2 vbuf[8]; int tt[8];
#pragma unroll
        for (int j = 0; j < 8; ++j) {
            int k = k0 + j;
            int rr = __shfl(myr, k);
            tt[j]  = __shfl(myt, k);
            vbuf[j] = make_float2(0.0f, 0.0f);
            if (k < n && lane < 48)
                vbuf[j] = ((const float2*)(feats + (size_t)rr * C_))[lane];
        }
#pragma unroll
        for (int j = 0; j < 8; ++j) {
            int k = k0 + j;
            if (k >= n) break;
            if (tt[j] != cur) {
                if (cur >= 0)
                    flush_run2(cur, run_start, k, n, ax, ay, lane, segstart, cnt, out, cnt_out);
                cur = tt[j]; run_start = k; ax = 0.0f; ay = 0.0f;
            }
            ax += vbuf[j].x; ay += vbuf[j].y;
        }
    }
    flush_run2(cur, run_start, n, n, ax, ay, lane, segstart, cnt, out, cnt_out);
}

__global__ void finalize_kernel(const int* __restrict__ wl,
                                const int* __restrict__ wlcount,
                                const int* __restrict__ cnt,
                                float* __restrict__ out,
                                float* __restrict__ cnt_out) {
    int idx  = (blockIdx.x * blockDim.x + threadIdx.x) >> 6;
    int lane = threadIdx.x & 63;
    if (idx >= wlcount[0]) return;
    int vox = wl[idx];
    int c = cnt[vox];
    float denom = (float)c + 0.0001f;
    if (lane < 48) {
        float2* o = (float2*)(out + (size_t)vox * C_);
        float2 x = o[lane];
        x.x /= denom; x.y /= denom;
        o[lane] = x;
    }
    if (lane == 0) cnt_out[vox] = (float)c;
}

extern "C" void kernel_launch(void* const* d_in, const int* in_sizes, int n_in,
                              void* d_out, int out_size, void* d_ws, size_t ws_size,
                              hipStream_t stream) {
    const float* feats  = (const float*)d_in[0];
    const int*   coords = (const int*)d_in[1];
    const float* vm     = (const float*)d_in[2];
    const float* intr   = (const float*)d_in[3];

    float* out     = (float*)d_out;                  // NVOX*C_ floats
    float* cnt_out = out + (size_t)NVOX * C_;        // NVOX floats

    char* ws = (char*)d_ws;
    int*                sneg    = (int*)(ws + 0);            // 24 B (pad to 64)
    int*                cnt     = (int*)(ws + 64);           // 800,000 B
    unsigned long long* mask    = (unsigned long long*)(ws + 800064); // 524,288 B
    int*                gtotal  = (int*)(ws + 1324352);      // 4 B
    int*                wlcount = (int*)(ws + 1324356);      // 4 B
    int*  tgt       = (int*)(ws + 1324416);                  // 614,400 B
    int*  segstart  = (int*)(ws + 1938816);                  // 800,000 B
    int*  cursor    = (int*)(ws + 2738816);                  // 800,000 B
    int*  wl        = (int*)(ws + 3538816);                  // 19,200 B
    int2* sorted_rt = (int2*)(ws + 3558016);                 // 1,228,800 B
    int*  occ       = (int*)(ws + 4786816);                  // 33,554,432 B (mask-gated)

    // ---- cooperative grid size from the runtime's own occupancy opinion ----
    static int coop_grid = -2;      // -2 unqueried, -1 disabled, >0 usable
    if (coop_grid == -2) {
        int nb = 0, ncu = 0, dev = 0;
        hipError_t e1 = hipGetDevice(&dev);
        hipError_t e2 = hipOccupancyMaxActiveBlocksPerMultiprocessor(
            &nb, (const void*)mega_kernel, 256, 0);
        hipError_t e3 = hipDeviceGetAttribute(
            &ncu, hipDeviceAttributeMultiprocessorCount, dev);
        if (e1 == hipSuccess && e2 == hipSuccess && e3 == hipSuccess &&
            nb > 0 && ncu > 0) {
            int g = nb * ncu;
            coop_grid = g > 1024 ? 1024 : g;
        } else {
            coop_grid = -1;
            (void)hipGetLastError();
        }
    }

    if (coop_grid > 0) {
        void* kargs[] = { (void*)&feats, (void*)&coords, (void*)&vm, (void*)&intr,
                          (void*)&sneg, (void*)&cnt, (void*)&mask, (void*)&gtotal,
                          (void*)&wlcount, (void*)&tgt, (void*)&segstart, (void*)&cursor,
                          (void*)&wl, (void*)&sorted_rt, (void*)&occ,
                          (void*)&out, (void*)&cnt_out };
        hipError_t e = hipLaunchCooperativeKernel((const void*)mega_kernel,
                                                  dim3(coop_grid), dim3(256),
                                                  kargs, 0, stream);
        if (e == hipSuccess) return;
        (void)hipGetLastError();    // clear sticky error, disable coop path
        coop_grid = -1;
    }

    // ---------------- fallback: verified multi-kernel path ------------------
    (void)hipMemsetAsync(ws, 0, 1324360, stream);
    (void)hipMemsetAsync(d_out, 0, (size_t)NVOX * (C_ + 1) * sizeof(float), stream);
    shift_kernel<<<NB1, 256, 0, stream>>>(coords, sneg);
    occ_kernel<<<NB1, 256, 0, stream>>>(coords, sneg, occ, mask);
    march_kernel<<<(NRAYS * 4 + 255) / 256, 256, 0, stream>>>(vm, intr, sneg, mask, occ, tgt, cnt);
    alloc_kernel<<<NB1, 256, 0, stream>>>(cnt, gtotal, segstart, cursor, wl, wlcount);
    order_kernel<<<NRAYS / 256, 256, 0, stream>>>(tgt, cursor, sorted_rt);
    chunk_reduce_kernel<<<(NCHUNK * 64 + 255) / 256, 256, 0, stream>>>(
        feats, sorted_rt, segstart, cnt, gtotal, out, cnt_out);
    finalize_kernel<<<(NCHUNK * 64 + 255) / 256, 256, 0, stream>>>(
        wl, wlcount, cnt, out, cnt_out);
}

// Round 5
// 229.784 us; speedup vs baseline: 2.6259x; 2.6259x over previous
//
#include <hip/hip_runtime.h>
#include <hip/hip_bf16.h>
#include <climits>

#define B_ 2
#define V_ 4
#define H_ 120
#define W_ 160
#define C_ 96
#define NVOX 200000
#define GRID_ 128
#define NSTEPS 156
#define NRAYS (B_*V_*H_*W_)       // 153600
#define NB1 ((NVOX + 255) / 256)  // 782 blocks over voxels
#define CHUNK 32                  // sorted-list entries per wave in chunk_reduce
#define NCHUNK ((NRAYS + CHUNK - 1) / CHUNK)  // 4800 max chunks
#define MASKW (B_ * GRID_ * GRID_ * GRID_ / 64)   // 65536 u64 words
#define OUTQ ((NVOX * (C_ + 1)) / 4)              // 4,850,000 float4s in d_out
#define NTHREADS_MARCH (2400 * 256)               // march grid: exactly 614400

// NOTE (round-4 post-mortem): a fully fused hipLaunchCooperativeKernel version
// ran at 893us with VALUBusy 2.1% — cg::grid.sync() costs ~100us/call on this
// 8-XCD part (cross-XCD barrier + L2 flush per sync). Kernel boundaries ARE
// the cheap grid barrier here. This version instead trims stream ops 9 -> 8:
//   - ws zeroing (cnt/mask/gtotal/wlcount) folded into shift_kernel
//   - 77.6MB d_out zeroing folded into march_kernel's tail (latency-bound,
//     stores ride idle BW); ws memset shrinks to 64B (sneg only).

// ---- Kernel A: ws zeroing + per-batch min via atomicMax(127-coord) ---------
// sneg zeroed by the 64B host memset (can't self-zero: other blocks atomicMax
// it concurrently). cnt/mask/gtotal/wlcount consumers are >=1 kernel boundary
// downstream, so plain-store zeroing here is safe.
__global__ void shift_kernel(const int* __restrict__ coords,
                             int* __restrict__ sneg,
                             int* __restrict__ cnt,
                             unsigned long long* __restrict__ mask,
                             int* __restrict__ gtotal,
                             int* __restrict__ wlcount) {
    __shared__ int smax[B_ * 3];
    int t = threadIdx.x;
    int i = blockIdx.x * blockDim.x + t;
    if (i < NVOX) cnt[i] = 0;
    if (i < MASKW) mask[i] = 0ull;
    if (i == 0) { *gtotal = 0; *wlcount = 0; }
    if (t < B_ * 3) smax[t] = 0;
    __syncthreads();
    if (i < NVOX) {
        int b = coords[i * 4 + 0];
        atomicMax(&smax[b * 3 + 0], 127 - coords[i * 4 + 1]);
        atomicMax(&smax[b * 3 + 1], 127 - coords[i * 4 + 2]);
        atomicMax(&smax[b * 3 + 2], 127 - coords[i * 4 + 3]);
    }
    __syncthreads();
    if (t < B_ * 3 && smax[t] > 0) atomicMax(&sneg[t], smax[t]);
}

// ------- Kernel B: occ id grid (last-dup wins) + 64-bit occupancy bitmask ---
// occ is NOT pre-initialized (poison irrelevant: mask gates all reads).
__global__ void occ_kernel(const int* __restrict__ coords,
                           const int* __restrict__ sneg,
                           int* __restrict__ occ,
                           unsigned long long* __restrict__ mask) {
    int i = blockIdx.x * blockDim.x + threadIdx.x;
    if (i >= NVOX) return;
    int b = coords[i * 4 + 0];
    int x = coords[i * 4 + 1] - (127 - sneg[b * 3 + 0]);
    int y = coords[i * 4 + 2] - (127 - sneg[b * 3 + 1]);
    int z = coords[i * 4 + 3] - (127 - sneg[b * 3 + 2]);
    int idx = ((b * GRID_ + z) * GRID_ + y) * GRID_ + x;
    atomicMax(&occ[idx], i);
    atomicOr(&mask[idx >> 6], 1ull << (idx & 63));
}

// -------- Kernel C: step-parallel march + WAVE-AGGREGATED cnt update --------
// Wave = 16 consecutive pixels x 4 step-blocks of 8 steps. One atomicAdd per
// contiguous equal-target run across the 16 result lanes. Tail: zero d_out
// (77.6 MB) — march is latency-bound, the streaming stores fill idle BW, and
// out isn't consumed until chunk_reduce (3 kernel boundaries later).
__global__ void march_kernel(const float* __restrict__ vm,
                             const float* __restrict__ intr,
                             const int* __restrict__ sneg,
                             const unsigned long long* __restrict__ mask,
                             const int* __restrict__ occ,
                             int* __restrict__ tgt,
                             int* __restrict__ cnt,
                             float* __restrict__ out) {
    int gt   = blockIdx.x * blockDim.x + threadIdx.x;
    int lane = threadIdx.x & 63;
    int p    = lane & 15;
    int sub  = lane >> 4;
    int r    = ((gt >> 6) << 4) + p;   // grid exactly covers NRAYS: no return
    {
        int w = r % W_;
        int h = (r / W_) % H_;
        int v = (r / (W_ * H_)) % V_;
        int b = r / (W_ * H_ * V_);
        const float* M = vm + (size_t)(b * V_ + v) * 16;
        float fx = intr[0], fy = intr[1], cx = intr[2], cy = intr[3];
        float dx = ((float)w + 0.5f - cx) / fx;
        float dy = ((float)h + 0.5f - cy) / fy;
        // d = R * (dx, dy, 1)
        float d0 = M[0] * dx + M[1] * dy + M[2];
        float d1 = M[4] * dx + M[5] * dy + M[6];
        float d2 = M[8] * dx + M[9] * dy + M[10];
        float t0 = M[3]  - (float)(127 - sneg[b * 3 + 0]);
        float t1 = M[7]  - (float)(127 - sneg[b * 3 + 1]);
        float t2 = M[11] - (float)(127 - sneg[b * 3 + 2]);
        const int vbase = b * GRID_ * GRID_ * GRID_;
        const int MISS = 0x7FFFFFFF;
        int beststep = MISS;
        for (int w0 = 0; w0 < NSTEPS; w0 += 32) {
            int lin[8]; bool ok[8];
#pragma unroll
            for (int j = 0; j < 8; ++j) {
                int st = w0 + sub * 8 + j;
                float t = 2.0f + 0.5f * (float)st;
                float pwx = d0 * t + t0;
                float pwy = d1 * t + t1;
                float pwz = d2 * t + t2;
                int ix = (int)floorf(pwx);
                int iy = (int)floorf(pwy);
                int iz = (int)floorf(pwz);
                ok[j] = ((unsigned)ix < (unsigned)GRID_) &
                        ((unsigned)iy < (unsigned)GRID_) &
                        ((unsigned)iz < (unsigned)GRID_) & (st < NSTEPS);
                int cix = min(max(ix, 0), GRID_ - 1);
                int ciy = min(max(iy, 0), GRID_ - 1);
                int ciz = min(max(iz, 0), GRID_ - 1);
                lin[j] = vbase + (ciz << 14) + (ciy << 7) + cix;
            }
            unsigned long long u[8];
            bool same[8];
            same[0] = false;
#pragma unroll
            for (int j = 1; j < 8; ++j) same[j] = ((lin[j] >> 6) == (lin[j - 1] >> 6));
#pragma unroll
            for (int j = 0; j < 8; ++j)
                if (!same[j]) u[j] = mask[lin[j] >> 6];
#pragma unroll
            for (int j = 1; j < 8; ++j)
                if (same[j]) u[j] = u[j - 1];
            int local = MISS;
#pragma unroll
            for (int j = 0; j < 8; ++j) {
                int st = w0 + sub * 8 + j;
                if (ok[j] && ((u[j] >> (lin[j] & 63)) & 1ull)) local = min(local, st);
            }
            local = min(local, __shfl_xor(local, 16));
            local = min(local, __shfl_xor(local, 32));
            if (local != MISS) { beststep = local; break; }
        }
        // resolve first-hit id (only the 16 result lanes read occ)
        int res = -1;
        if (sub == 0) {
            if (beststep != MISS) {
                float t = 2.0f + 0.5f * (float)beststep;
                int ix = (int)floorf(d0 * t + t0);
                int iy = (int)floorf(d1 * t + t1);
                int iz = (int)floorf(d2 * t + t2);
                res = occ[vbase + (iz << 14) + (iy << 7) + ix];
            }
            tgt[r] = res;
        }
        // wave-aggregated histogram: one atomic per contiguous equal-target run
        bool active = (sub == 0) && (res >= 0);
        int prevres = __shfl_up(res, 1);
        bool head = active && (p == 0 || prevres != res);
        bool boundary = head || !active;
        unsigned long long bb = __ballot(boundary);
        if (head) {
            unsigned long long above = bb & ~((2ull << lane) - 1);  // boundaries > lane
            int next = above ? (__ffsll((long long)above) - 1) : 64;
            atomicAdd(&cnt[res], next - lane);                      // run length
        }
    }
    // ---- folded d_out zero (replaces a 13us standalone fill dispatch) ------
    float4 z4 = make_float4(0.f, 0.f, 0.f, 0.f);
    float4* o4 = (float4*)out;
    for (int i = gt; i < OUTQ; i += NTHREADS_MARCH) o4[i] = z4;
}

// ---- Kernel D: segment allocator + crossing worklist -----------------------
__global__ void alloc_kernel(const int* __restrict__ cnt,
                             int* __restrict__ gtotal,
                             int* __restrict__ segstart,
                             int* __restrict__ cursor,
                             int* __restrict__ wl,
                             int* __restrict__ wlcount) {
    __shared__ int wtot[4];
    int tid  = threadIdx.x;
    int lane = tid & 63;
    int wid  = tid >> 6;
    int i = blockIdx.x * 256 + tid;
    int c = (i < NVOX) ? cnt[i] : 0;
    int x = c;
#pragma unroll
    for (int d = 1; d < 64; d <<= 1) {
        int y = __shfl_up(x, d);
        if (lane >= d) x += y;
    }
    if (lane == 63) wtot[wid] = x;
    __syncthreads();
    if (tid == 0) {
        int s0 = wtot[0], s1 = wtot[1], s2 = wtot[2], s3 = wtot[3];
        int base = atomicAdd(gtotal, s0 + s1 + s2 + s3);
        wtot[0] = base;
        wtot[1] = base + s0;
        wtot[2] = base + s0 + s1;
        wtot[3] = base + s0 + s1 + s2;
    }
    __syncthreads();
    if (i >= NVOX) return;
    int s = wtot[wid] + (x - c);
    segstart[i] = s;
    cursor[i]   = s;
    if (c > 0 && (s / CHUNK) != ((s + c - 1) / CHUNK)) {
        int pidx = atomicAdd(wlcount, 1);
        wl[pidx] = i;                 // crossing voxel -> finalize worklist
    }
}

// ---- Kernel E: wave-aggregated bucket scatter ------------------------------
__global__ void order_kernel(const int* __restrict__ tgt,
                             int* __restrict__ cursor, int2* __restrict__ sorted_rt) {
    int r = blockIdx.x * blockDim.x + threadIdx.x;   // grid is exactly NRAYS
    int lane = threadIdx.x & 63;
    int t = tgt[r];
    bool active = t >= 0;
    int prev = __shfl_up(t, 1);
    bool head = active && (lane == 0 || prev != t);
    bool boundary = head || !active;
    unsigned long long bb = __ballot(boundary);
    unsigned long long below = bb & ((2ull << lane) - 1);   // bits 0..lane
    int headpos = 63 - __clzll(below | 1ull);               // nearest boundary <= lane
    int base = 0;
    if (head) {
        unsigned long long above = bb & ~((2ull << lane) - 1);  // bits > lane
        int next = above ? (__ffsll((long long)above) - 1) : 64;
        int runlen = next - lane;
        base = atomicAdd(&cursor[t], runlen);
    }
    base = __shfl(base, headpos);
    if (active) sorted_rt[base + (lane - headpos)] = make_int2(r, t);
}

// ---------------- run flush: middle runs need no cnt/segstart ---------------
__device__ __forceinline__ void flush_run2(int t, int ks, int ke, int n,
                                           float ax, float ay, int lane,
                                           const int* __restrict__ segstart,
                                           const int* __restrict__ cnt,
                                           float* __restrict__ out,
                                           float* __restrict__ cnt_out) {
    int c;
    bool complete;
    if (ks > 0 && ke < n) {          // middle run: whole segment inside chunk
        c = ke - ks;
        complete = true;
    } else {
        c = cnt[t];
        int s = segstart[t];
        complete = (s / CHUNK) == ((s + c - 1) / CHUNK);
    }
    if (complete) {
        float denom = (float)c + 0.0001f;
        if (lane < 48) {
            float2 wv; wv.x = ax / denom; wv.y = ay / denom;
            ((float2*)(out + (size_t)t * C_))[lane] = wv;
        }
        if (lane == 0) cnt_out[t] = (float)c;
    } else if (lane < 48) {          // crossing: accumulate into zeroed row
        unsafeAtomicAdd(out + (size_t)t * C_ + 2 * lane,     ax);
        unsafeAtomicAdd(out + (size_t)t * C_ + 2 * lane + 1, ay);
    }
}

// ---------------- Kernel F: chunked segmented reduce (8-deep pipeline) ------
__global__ void chunk_reduce_kernel(const float* __restrict__ feats,
                                    const int2* __restrict__ sorted_rt,
                                    const int* __restrict__ segstart,
                                    const int* __restrict__ cnt,
                                    const int* __restrict__ total_p,
                                    float* __restrict__ out,
                                    float* __restrict__ cnt_out) {
    int wave = (blockIdx.x * blockDim.x + threadIdx.x) >> 6;
    int lane = threadIdx.x & 63;
    int total = total_p[0];
    int a = wave * CHUNK;
    if (a >= total) return;
    int n = min(CHUNK, total - a);
    int myr = 0, myt = 0;
    if (lane < n) { int2 e = sorted_rt[a + lane]; myr = e.x; myt = e.y; }
    float ax = 0.0f, ay = 0.0f;
    int cur = -1, run_start = 0;
    for (int k0 = 0; k0 < n; k0 += 8) {
        float2 vbuf[8]; int tt[8];
#pragma unroll
        for (int j = 0; j < 8; ++j) {             // issue 8 feature loads
            int k = k0 + j;
            int rr = __shfl(myr, k);
            tt[j]  = __shfl(myt, k);
            vbuf[j] = make_float2(0.0f, 0.0f);
            if (k < n && lane < 48)
                vbuf[j] = ((const float2*)(feats + (size_t)rr * C_))[lane];
        }
#pragma unroll
        for (int j = 0; j < 8; ++j) {
            int k = k0 + j;
            if (k >= n) break;
            if (tt[j] != cur) {
                if (cur >= 0)
                    flush_run2(cur, run_start, k, n, ax, ay, lane, segstart, cnt, out, cnt_out);
                cur = tt[j]; run_start = k; ax = 0.0f; ay = 0.0f;
            }
            ax += vbuf[j].x; ay += vbuf[j].y;
        }
    }
    flush_run2(cur, run_start, n, n, ax, ay, lane, segstart, cnt, out, cnt_out);
}

// ---- Kernel G: finalize crossing voxels from worklist ----------------------
// Empty rows + empty cnt_out covered by march's folded d_out zeroing.
__global__ void finalize_kernel(const int* __restrict__ wl,
                                const int* __restrict__ wlcount,
                                const int* __restrict__ cnt,
                                float* __restrict__ out,
                                float* __restrict__ cnt_out) {
    int idx  = (blockIdx.x * blockDim.x + threadIdx.x) >> 6;
    int lane = threadIdx.x & 63;
    if (idx >= wlcount[0]) return;
    int vox = wl[idx];
    int c = cnt[vox];
    float denom = (float)c + 0.0001f;
    if (lane < 48) {
        float2* o = (float2*)(out + (size_t)vox * C_);
        float2 x = o[lane];
        x.x /= denom; x.y /= denom;
        o[lane] = x;
    }
    if (lane == 0) cnt_out[vox] = (float)c;
}

extern "C" void kernel_launch(void* const* d_in, const int* in_sizes, int n_in,
                              void* d_out, int out_size, void* d_ws, size_t ws_size,
                              hipStream_t stream) {
    const float* feats  = (const float*)d_in[0];
    const int*   coords = (const int*)d_in[1];
    const float* vm     = (const float*)d_in[2];
    const float* intr   = (const float*)d_in[3];

    float* out     = (float*)d_out;                  // NVOX*C_ floats
    float* cnt_out = out + (size_t)NVOX * C_;        // NVOX floats

    char* ws = (char*)d_ws;
    int*                sneg    = (int*)(ws + 0);            // 24 B (pad to 64) — memset-zeroed
    int*                cnt     = (int*)(ws + 64);           // 800,000 B — zeroed in shift
    unsigned long long* mask    = (unsigned long long*)(ws + 800064); // 524,288 B — zeroed in shift
    int*                gtotal  = (int*)(ws + 1324352);      // 4 B — zeroed in shift
    int*                wlcount = (int*)(ws + 1324356);      // 4 B — zeroed in shift
    int*  tgt       = (int*)(ws + 1324416);                  // 614,400 B
    int*  segstart  = (int*)(ws + 1938816);                  // 800,000 B
    int*  cursor    = (int*)(ws + 2738816);                  // 800,000 B
    int*  wl        = (int*)(ws + 3538816);                  // 19,200 B
    int2* sorted_rt = (int2*)(ws + 3558016);                 // 1,228,800 B
    int*  occ       = (int*)(ws + 4786816);                  // 33,554,432 B (mask-gated)

    (void)hipMemsetAsync(ws, 0, 64, stream);                 // sneg only

    shift_kernel<<<NB1, 256, 0, stream>>>(coords, sneg, cnt, mask, gtotal, wlcount);
    occ_kernel<<<NB1, 256, 0, stream>>>(coords, sneg, occ, mask);
    march_kernel<<<2400, 256, 0, stream>>>(vm, intr, sneg, mask, occ, tgt, cnt, out);
    alloc_kernel<<<NB1, 256, 0, stream>>>(cnt, gtotal, segstart, cursor, wl, wlcount);
    order_kernel<<<NRAYS / 256, 256, 0, stream>>>(tgt, cursor, sorted_rt);
    chunk_reduce_kernel<<<(NCHUNK * 64 + 255) / 256, 256, 0, stream>>>(
        feats, sorted_rt, segstart, cnt, gtotal, out, cnt_out);
    finalize_kernel<<<(NCHUNK * 64 + 255) / 256, 256, 0, stream>>>(
        wl, wlcount, cnt, out, cnt_out);
}

// Round 6
// 220.059 us; speedup vs baseline: 2.7419x; 1.0442x over previous
//
#include <hip/hip_runtime.h>
#include <hip/hip_bf16.h>
#include <climits>

#define B_ 2
#define V_ 4
#define H_ 120
#define W_ 160
#define C_ 96
#define NVOX 200000
#define GRID_ 128
#define NSTEPS 156
#define NRAYS (B_*V_*H_*W_)       // 153600
#define NB1 ((NVOX + 255) / 256)  // 782 blocks over voxels
#define CHUNK 32                  // sorted-list entries per wave in chunk_reduce
#define NCHUNK ((NRAYS + CHUNK - 1) / CHUNK)  // 4800 max chunks
#define OUTQ2 ((NVOX * C_) / 4)   // 4,800,000 float4s: out rows only (cnt_out
                                  // written exhaustively by alloc_kernel)
#define NTHREADS_MARCH (2400 * 256)

// NOTE (round-5 post-mortem): boundaries are ~5us not ~13us; fusion-with-
// grid.sync is 100us/sync (round 4) — kernel boundaries stay. This round:
// the per-batch SHIFT is a provable no-op (s integer => floor(pw-s) =
// floor(pw)-s; hit set identical; divergent bounds regions contain no
// voxels). shift_kernel deleted entirely: occ/march use raw coords / raw
// view-matrix translation. alloc now writes cnt_out for ALL voxels, so
// march's folded zero covers only the out-row region.

// ------- Kernel B: occ id grid (last-dup wins) + 64-bit occupancy bitmask ---
// occ is NOT pre-initialized (poison irrelevant: mask gates all reads).
// Raw coords: no shift (see note above).
__global__ void occ_kernel(const int* __restrict__ coords,
                           int* __restrict__ occ,
                           unsigned long long* __restrict__ mask) {
    int i = blockIdx.x * blockDim.x + threadIdx.x;
    if (i >= NVOX) return;
    int b = coords[i * 4 + 0];
    int x = coords[i * 4 + 1];
    int y = coords[i * 4 + 2];
    int z = coords[i * 4 + 3];
    int idx = ((b * GRID_ + z) * GRID_ + y) * GRID_ + x;
    atomicMax(&occ[idx], i);        // last-dup wins == max ray id
    atomicOr(&mask[idx >> 6], 1ull << (idx & 63));
}

// -------- Kernel C: step-parallel march + WAVE-AGGREGATED cnt update --------
// Wave = 16 consecutive pixels x 4 step-blocks of 8 steps. One atomicAdd per
// contiguous equal-target run across the 16 result lanes. Tail: zero the
// 76.8MB out-row region (march is latency-bound; stores ride idle BW; out
// isn't consumed until chunk_reduce, 2 boundaries later).
__global__ void march_kernel(const float* __restrict__ vm,
                             const float* __restrict__ intr,
                             const unsigned long long* __restrict__ mask,
                             const int* __restrict__ occ,
                             int* __restrict__ tgt,
                             int* __restrict__ cnt,
                             float* __restrict__ out) {
    int gt   = blockIdx.x * blockDim.x + threadIdx.x;
    int lane = threadIdx.x & 63;
    int p    = lane & 15;
    int sub  = lane >> 4;
    int r    = ((gt >> 6) << 4) + p;   // grid exactly covers NRAYS
    {
        int w = r % W_;
        int h = (r / W_) % H_;
        int v = (r / (W_ * H_)) % V_;
        int b = r / (W_ * H_ * V_);
        const float* M = vm + (size_t)(b * V_ + v) * 16;
        float fx = intr[0], fy = intr[1], cx = intr[2], cy = intr[3];
        float dx = ((float)w + 0.5f - cx) / fx;
        float dy = ((float)h + 0.5f - cy) / fy;
        // d = R * (dx, dy, 1); t = raw translation (no shift — see note)
        float d0 = M[0] * dx + M[1] * dy + M[2];
        float d1 = M[4] * dx + M[5] * dy + M[6];
        float d2 = M[8] * dx + M[9] * dy + M[10];
        float t0 = M[3];
        float t1 = M[7];
        float t2 = M[11];
        const int vbase = b * GRID_ * GRID_ * GRID_;
        const int MISS = 0x7FFFFFFF;
        int beststep = MISS;
        for (int w0 = 0; w0 < NSTEPS; w0 += 32) {
            int lin[8]; bool ok[8];
#pragma unroll
            for (int j = 0; j < 8; ++j) {
                int st = w0 + sub * 8 + j;
                float t = 2.0f + 0.5f * (float)st;
                float pwx = d0 * t + t0;
                float pwy = d1 * t + t1;
                float pwz = d2 * t + t2;
                int ix = (int)floorf(pwx);
                int iy = (int)floorf(pwy);
                int iz = (int)floorf(pwz);
                ok[j] = ((unsigned)ix < (unsigned)GRID_) &
                        ((unsigned)iy < (unsigned)GRID_) &
                        ((unsigned)iz < (unsigned)GRID_) & (st < NSTEPS);
                int cix = min(max(ix, 0), GRID_ - 1);
                int ciy = min(max(iy, 0), GRID_ - 1);
                int ciz = min(max(iz, 0), GRID_ - 1);
                lin[j] = vbase + (ciz << 14) + (ciy << 7) + cix;
            }
            unsigned long long u[8];
            bool same[8];
            same[0] = false;
#pragma unroll
            for (int j = 1; j < 8; ++j) same[j] = ((lin[j] >> 6) == (lin[j - 1] >> 6));
#pragma unroll
            for (int j = 0; j < 8; ++j)
                if (!same[j]) u[j] = mask[lin[j] >> 6];
#pragma unroll
            for (int j = 1; j < 8; ++j)
                if (same[j]) u[j] = u[j - 1];
            int local = MISS;
#pragma unroll
            for (int j = 0; j < 8; ++j) {
                int st = w0 + sub * 8 + j;
                if (ok[j] && ((u[j] >> (lin[j] & 63)) & 1ull)) local = min(local, st);
            }
            local = min(local, __shfl_xor(local, 16));
            local = min(local, __shfl_xor(local, 32));
            if (local != MISS) { beststep = local; break; }
        }
        // resolve first-hit id (only the 16 result lanes read occ)
        int res = -1;
        if (sub == 0) {
            if (beststep != MISS) {
                float t = 2.0f + 0.5f * (float)beststep;
                int ix = (int)floorf(d0 * t + t0);
                int iy = (int)floorf(d1 * t + t1);
                int iz = (int)floorf(d2 * t + t2);
                res = occ[vbase + (iz << 14) + (iy << 7) + ix];
            }
            tgt[r] = res;
        }
        // wave-aggregated histogram: one atomic per contiguous equal-target run
        bool active = (sub == 0) && (res >= 0);
        int prevres = __shfl_up(res, 1);
        bool head = active && (p == 0 || prevres != res);
        bool boundary = head || !active;
        unsigned long long bb = __ballot(boundary);
        if (head) {
            unsigned long long above = bb & ~((2ull << lane) - 1);  // boundaries > lane
            int next = above ? (__ffsll((long long)above) - 1) : 64;
            atomicAdd(&cnt[res], next - lane);                      // run length
        }
    }
    // ---- folded zero of the out-row region (76.8 MB) -----------------------
    float4 z4 = make_float4(0.f, 0.f, 0.f, 0.f);
    float4* o4 = (float4*)out;
    for (int i = gt; i < OUTQ2; i += NTHREADS_MARCH) o4[i] = z4;
}

// ---- Kernel D: segment allocator + crossing worklist + cnt_out write -------
// Writes cnt_out for EVERY voxel (reads cnt[i] anyway) — removes scattered
// cnt_out stores from chunk/finalize and shrinks the zero-fill obligation.
__global__ void alloc_kernel(const int* __restrict__ cnt,
                             int* __restrict__ gtotal,
                             int* __restrict__ segstart,
                             int* __restrict__ cursor,
                             int* __restrict__ wl,
                             int* __restrict__ wlcount,
                             float* __restrict__ cnt_out) {
    __shared__ int wtot[4];
    int tid  = threadIdx.x;
    int lane = tid & 63;
    int wid  = tid >> 6;
    int i = blockIdx.x * 256 + tid;
    int c = (i < NVOX) ? cnt[i] : 0;
    int x = c;
#pragma unroll
    for (int d = 1; d < 64; d <<= 1) {
        int y = __shfl_up(x, d);
        if (lane >= d) x += y;
    }
    if (lane == 63) wtot[wid] = x;
    __syncthreads();
    if (tid == 0) {
        int s0 = wtot[0], s1 = wtot[1], s2 = wtot[2], s3 = wtot[3];
        int base = atomicAdd(gtotal, s0 + s1 + s2 + s3);
        wtot[0] = base;
        wtot[1] = base + s0;
        wtot[2] = base + s0 + s1;
        wtot[3] = base + s0 + s1 + s2;
    }
    __syncthreads();
    if (i >= NVOX) return;
    cnt_out[i] = (float)c;
    int s = wtot[wid] + (x - c);
    segstart[i] = s;
    cursor[i]   = s;
    if (c > 0 && (s / CHUNK) != ((s + c - 1) / CHUNK)) {
        int pidx = atomicAdd(wlcount, 1);
        wl[pidx] = i;                 // crossing voxel -> finalize worklist
    }
}

// ---- Kernel E: wave-aggregated bucket scatter ------------------------------
__global__ void order_kernel(const int* __restrict__ tgt,
                             int* __restrict__ cursor, int2* __restrict__ sorted_rt) {
    int r = blockIdx.x * blockDim.x + threadIdx.x;   // grid is exactly NRAYS
    int lane = threadIdx.x & 63;
    int t = tgt[r];
    bool active = t >= 0;
    int prev = __shfl_up(t, 1);
    bool head = active && (lane == 0 || prev != t);
    bool boundary = head || !active;
    unsigned long long bb = __ballot(boundary);
    unsigned long long below = bb & ((2ull << lane) - 1);   // bits 0..lane
    int headpos = 63 - __clzll(below | 1ull);               // nearest boundary <= lane
    int base = 0;
    if (head) {
        unsigned long long above = bb & ~((2ull << lane) - 1);  // bits > lane
        int next = above ? (__ffsll((long long)above) - 1) : 64;
        int runlen = next - lane;
        base = atomicAdd(&cursor[t], runlen);
    }
    base = __shfl(base, headpos);
    if (active) sorted_rt[base + (lane - headpos)] = make_int2(r, t);
}

// ---------------- run flush: middle runs need no cnt/segstart ---------------
__device__ __forceinline__ void flush_run2(int t, int ks, int ke, int n,
                                           float ax, float ay, int lane,
                                           const int* __restrict__ segstart,
                                           const int* __restrict__ cnt,
                                           float* __restrict__ out) {
    int c;
    bool complete;
    if (ks > 0 && ke < n) {          // middle run: whole segment inside chunk
        c = ke - ks;
        complete = true;
    } else {
        c = cnt[t];
        int s = segstart[t];
        complete = (s / CHUNK) == ((s + c - 1) / CHUNK);
    }
    if (complete) {
        float denom = (float)c + 0.0001f;
        if (lane < 48) {
            float2 wv; wv.x = ax / denom; wv.y = ay / denom;
            ((float2*)(out + (size_t)t * C_))[lane] = wv;
        }
    } else if (lane < 48) {          // crossing: accumulate into zeroed row
        unsafeAtomicAdd(out + (size_t)t * C_ + 2 * lane,     ax);
        unsafeAtomicAdd(out + (size_t)t * C_ + 2 * lane + 1, ay);
    }
}

// ---------------- Kernel F: chunked segmented reduce (8-deep pipeline) ------
__global__ void chunk_reduce_kernel(const float* __restrict__ feats,
                                    const int2* __restrict__ sorted_rt,
                                    const int* __restrict__ segstart,
                                    const int* __restrict__ cnt,
                                    const int* __restrict__ total_p,
                                    float* __restrict__ out) {
    int wave = (blockIdx.x * blockDim.x + threadIdx.x) >> 6;
    int lane = threadIdx.x & 63;
    int total = total_p[0];
    int a = wave * CHUNK;
    if (a >= total) return;
    int n = min(CHUNK, total - a);
    int myr = 0, myt = 0;
    if (lane < n) { int2 e = sorted_rt[a + lane]; myr = e.x; myt = e.y; }
    float ax = 0.0f, ay = 0.0f;
    int cur = -1, run_start = 0;
    for (int k0 = 0; k0 < n; k0 += 8) {
        float2 vbuf[8]; int tt[8];
#pragma unroll
        for (int j = 0; j < 8; ++j) {             // issue 8 feature loads
            int k = k0 + j;
            int rr = __shfl(myr, k);
            tt[j]  = __shfl(myt, k);
            vbuf[j] = make_float2(0.0f, 0.0f);
            if (k < n && lane < 48)
                vbuf[j] = ((const float2*)(feats + (size_t)rr * C_))[lane];
        }
#pragma unroll
        for (int j = 0; j < 8; ++j) {
            int k = k0 + j;
            if (k >= n) break;
            if (tt[j] != cur) {
                if (cur >= 0)
                    flush_run2(cur, run_start, k, n, ax, ay, lane, segstart, cnt, out);
                cur = tt[j]; run_start = k; ax = 0.0f; ay = 0.0f;
            }
            ax += vbuf[j].x; ay += vbuf[j].y;
        }
    }
    flush_run2(cur, run_start, n, n, ax, ay, lane, segstart, cnt, out);
}

// ---- Kernel G: finalize crossing voxels from worklist ----------------------
// Empty rows covered by march's folded zeroing; cnt_out fully by alloc.
__global__ void finalize_kernel(const int* __restrict__ wl,
                                const int* __restrict__ wlcount,
                                const int* __restrict__ cnt,
                                float* __restrict__ out) {
    int idx  = (blockIdx.x * blockDim.x + threadIdx.x) >> 6;
    int lane = threadIdx.x & 63;
    if (idx >= wlcount[0]) return;
    int vox = wl[idx];
    int c = cnt[vox];
    float denom = (float)c + 0.0001f;
    if (lane < 48) {
        float2* o = (float2*)(out + (size_t)vox * C_);
        float2 x = o[lane];
        x.x /= denom; x.y /= denom;
        o[lane] = x;
    }
}

extern "C" void kernel_launch(void* const* d_in, const int* in_sizes, int n_in,
                              void* d_out, int out_size, void* d_ws, size_t ws_size,
                              hipStream_t stream) {
    const float* feats  = (const float*)d_in[0];
    const int*   coords = (const int*)d_in[1];
    const float* vm     = (const float*)d_in[2];
    const float* intr   = (const float*)d_in[3];

    float* out     = (float*)d_out;                  // NVOX*C_ floats
    float* cnt_out = out + (size_t)NVOX * C_;        // NVOX floats

    char* ws = (char*)d_ws;
    // zero region (one 1.3MB memset): [unused 64B] | cnt | mask | gtotal | wlcount
    int*                cnt     = (int*)(ws + 64);           // 800,000 B
    unsigned long long* mask    = (unsigned long long*)(ws + 800064); // 524,288 B
    int*                gtotal  = (int*)(ws + 1324352);      // 4 B
    int*                wlcount = (int*)(ws + 1324356);      // 4 B -> zero ends 1324360
    int*  tgt       = (int*)(ws + 1324416);                  // 614,400 B
    int*  segstart  = (int*)(ws + 1938816);                  // 800,000 B
    int*  cursor    = (int*)(ws + 2738816);                  // 800,000 B
    int*  wl        = (int*)(ws + 3538816);                  // 19,200 B
    int2* sorted_rt = (int2*)(ws + 3558016);                 // 1,228,800 B
    int*  occ       = (int*)(ws + 4786816);                  // 33,554,432 B (mask-gated)

    (void)hipMemsetAsync(ws, 0, 1324360, stream);

    occ_kernel<<<NB1, 256, 0, stream>>>(coords, occ, mask);
    march_kernel<<<2400, 256, 0, stream>>>(vm, intr, mask, occ, tgt, cnt, out);
    alloc_kernel<<<NB1, 256, 0, stream>>>(cnt, gtotal, segstart, cursor, wl, wlcount, cnt_out);
    order_kernel<<<NRAYS / 256, 256, 0, stream>>>(tgt, cursor, sorted_rt);
    chunk_reduce_kernel<<<(NCHUNK * 64 + 255) / 256, 256, 0, stream>>>(
        feats, sorted_rt, segstart, cnt, gtotal, out);
    finalize_kernel<<<(NCHUNK * 64 + 255) / 256, 256, 0, stream>>>(
        wl, wlcount, cnt, out);
}

// Round 7
// 192.385 us; speedup vs baseline: 3.1363x; 1.1438x over previous
//
#include <hip/hip_runtime.h>
#include <hip/hip_bf16.h>
#include <climits>

#define B_ 2
#define V_ 4
#define H_ 120
#define W_ 160
#define C_ 96
#define NVOX 200000
#define GRID_ 128
#define NSTEPS 156
#define NRAYS (B_*V_*H_*W_)       // 153600
#define NB1 ((NVOX + 255) / 256)  // 782 blocks over voxels
#define CHUNK 32                  // rays per wave in scatter
#define OUTQ2 ((NVOX * C_) / 4)   // 4,800,000 float4s: out rows (cnt_out
                                  // written exhaustively by scatter tail)
#define NTHREADS_OCC (NB1 * 256)  // 200192
#define NTHREADS_MARCH (2400 * 256)

// NOTE (round-6 post-mortem): ~220us across 7 ops is mostly the dependent
// sort-machinery chain (alloc->order->chunk->finalize). Since cnt is COMPLETE
// after march, scatter can add PRE-DIVIDED values feats/(cnt[t]+1e-4) in ray
// order with in-wave run aggregation (adjacent pixels share first-hit voxels;
// hottest voxel ~1600 rays arrives in ~40-pixel scanline runs -> ~80 flushes
// per address, trivial L2 serialization). Sort pipeline deleted: 7 ops -> 4.
// feats rows are now read SEQUENTIALLY (ray order) instead of gathered.

// ------- Kernel A: occ id grid + 64-bit occupancy bitmask + d_out zero ------
// occ NOT pre-initialized (mask gates all reads). Raw coords: the reference's
// per-batch shift is a provable no-op (integer s => floor(pw-s)=floor(pw)-s,
// hit set identical). Tail: zero the 76.8MB out-row region (needed before
// scatter's atomics, 2 kernel boundaries downstream).
__global__ void occ_kernel(const int* __restrict__ coords,
                           int* __restrict__ occ,
                           unsigned long long* __restrict__ mask,
                           float* __restrict__ out) {
    int i = blockIdx.x * blockDim.x + threadIdx.x;
    if (i < NVOX) {
        int b = coords[i * 4 + 0];
        int x = coords[i * 4 + 1];
        int y = coords[i * 4 + 2];
        int z = coords[i * 4 + 3];
        int idx = ((b * GRID_ + z) * GRID_ + y) * GRID_ + x;
        atomicMax(&occ[idx], i);        // last-dup wins == max ray id
        atomicOr(&mask[idx >> 6], 1ull << (idx & 63));
    }
    float4 z4 = make_float4(0.f, 0.f, 0.f, 0.f);
    float4* o4 = (float4*)out;
    for (int q = blockIdx.x * blockDim.x + threadIdx.x; q < OUTQ2; q += NTHREADS_OCC)
        o4[q] = z4;
}

// -------- Kernel B: step-parallel march + WAVE-AGGREGATED cnt update --------
// Wave = 16 consecutive pixels x 4 step-blocks of 8 steps. One atomicAdd per
// contiguous equal-target run across the 16 result lanes.
__global__ void march_kernel(const float* __restrict__ vm,
                             const float* __restrict__ intr,
                             const unsigned long long* __restrict__ mask,
                             const int* __restrict__ occ,
                             int* __restrict__ tgt,
                             int* __restrict__ cnt) {
    int gt   = blockIdx.x * blockDim.x + threadIdx.x;
    int lane = threadIdx.x & 63;
    int p    = lane & 15;
    int sub  = lane >> 4;
    int r    = ((gt >> 6) << 4) + p;   // grid exactly covers NRAYS
    int w = r % W_;
    int h = (r / W_) % H_;
    int v = (r / (W_ * H_)) % V_;
    int b = r / (W_ * H_ * V_);
    const float* M = vm + (size_t)(b * V_ + v) * 16;
    float fx = intr[0], fy = intr[1], cx = intr[2], cy = intr[3];
    float dx = ((float)w + 0.5f - cx) / fx;
    float dy = ((float)h + 0.5f - cy) / fy;
    // d = R * (dx, dy, 1); t = raw translation (no shift — see note)
    float d0 = M[0] * dx + M[1] * dy + M[2];
    float d1 = M[4] * dx + M[5] * dy + M[6];
    float d2 = M[8] * dx + M[9] * dy + M[10];
    float t0 = M[3];
    float t1 = M[7];
    float t2 = M[11];
    const int vbase = b * GRID_ * GRID_ * GRID_;
    const int MISS = 0x7FFFFFFF;
    int beststep = MISS;
    for (int w0 = 0; w0 < NSTEPS; w0 += 32) {
        int lin[8]; bool ok[8];
#pragma unroll
        for (int j = 0; j < 8; ++j) {
            int st = w0 + sub * 8 + j;
            float t = 2.0f + 0.5f * (float)st;
            float pwx = d0 * t + t0;
            float pwy = d1 * t + t1;
            float pwz = d2 * t + t2;
            int ix = (int)floorf(pwx);
            int iy = (int)floorf(pwy);
            int iz = (int)floorf(pwz);
            ok[j] = ((unsigned)ix < (unsigned)GRID_) &
                    ((unsigned)iy < (unsigned)GRID_) &
                    ((unsigned)iz < (unsigned)GRID_) & (st < NSTEPS);
            int cix = min(max(ix, 0), GRID_ - 1);
            int ciy = min(max(iy, 0), GRID_ - 1);
            int ciz = min(max(iz, 0), GRID_ - 1);
            lin[j] = vbase + (ciz << 14) + (ciy << 7) + cix;
        }
        unsigned long long u[8];
        bool same[8];
        same[0] = false;
#pragma unroll
        for (int j = 1; j < 8; ++j) same[j] = ((lin[j] >> 6) == (lin[j - 1] >> 6));
#pragma unroll
        for (int j = 0; j < 8; ++j)
            if (!same[j]) u[j] = mask[lin[j] >> 6];
#pragma unroll
        for (int j = 1; j < 8; ++j)
            if (same[j]) u[j] = u[j - 1];
        int local = MISS;
#pragma unroll
        for (int j = 0; j < 8; ++j) {
            int st = w0 + sub * 8 + j;
            if (ok[j] && ((u[j] >> (lin[j] & 63)) & 1ull)) local = min(local, st);
        }
        local = min(local, __shfl_xor(local, 16));
        local = min(local, __shfl_xor(local, 32));
        if (local != MISS) { beststep = local; break; }
    }
    // resolve first-hit id (only the 16 result lanes read occ)
    int res = -1;
    if (sub == 0) {
        if (beststep != MISS) {
            float t = 2.0f + 0.5f * (float)beststep;
            int ix = (int)floorf(d0 * t + t0);
            int iy = (int)floorf(d1 * t + t1);
            int iz = (int)floorf(d2 * t + t2);
            res = occ[vbase + (iz << 14) + (iy << 7) + ix];
        }
        tgt[r] = res;
    }
    // wave-aggregated histogram: one atomic per contiguous equal-target run
    bool active = (sub == 0) && (res >= 0);
    int prevres = __shfl_up(res, 1);
    bool head = active && (p == 0 || prevres != res);
    bool boundary = head || !active;
    unsigned long long bb = __ballot(boundary);
    if (head) {
        unsigned long long above = bb & ~((2ull << lane) - 1);  // boundaries > lane
        int next = above ? (__ffsll((long long)above) - 1) : 64;
        atomicAdd(&cnt[res], next - lane);                      // run length
    }
}

// ---------------- run flush: pre-divided atomic accumulate ------------------
__device__ __forceinline__ void flush_run(int t, float ax, float ay, int lane,
                                          const int* __restrict__ cnt,
                                          float* __restrict__ out) {
    float denom = (float)cnt[t] + 0.0001f;   // same addr all lanes: broadcast
    if (lane < 48) {
        unsafeAtomicAdd(out + (size_t)t * C_ + 2 * lane,     ax / denom);
        unsafeAtomicAdd(out + (size_t)t * C_ + 2 * lane + 1, ay / denom);
    }
}

// ---------------- Kernel C: ray-order scatter (8-deep pipeline) -------------
// Wave = CHUNK consecutive rays; lane<48 = channel pair. feats rows stream
// SEQUENTIALLY. Runs of equal tgt (image-space coherence) are summed in
// registers and flushed with ONE pair of atomic instructions per run,
// pre-divided by cnt[t]+1e-4 (cnt complete after march). Tail: cnt_out.
__global__ void scatter_kernel(const float* __restrict__ feats,
                               const int* __restrict__ tgt,
                               const int* __restrict__ cnt,
                               float* __restrict__ out,
                               float* __restrict__ cnt_out) {
    int gthread = blockIdx.x * blockDim.x + threadIdx.x;
    int lane = threadIdx.x & 63;
    if (gthread < NVOX) cnt_out[gthread] = (float)cnt[gthread];  // grid >= NVOX
    int wave = gthread >> 6;
    int a = wave * CHUNK;                 // grid sized exactly: a < NRAYS
    int myt = (lane < CHUNK) ? tgt[a + lane] : -1;
    float ax = 0.0f, ay = 0.0f;
    int cur = -1;
    for (int k0 = 0; k0 < CHUNK; k0 += 8) {
        float2 vbuf[8]; int tt[8];
#pragma unroll
        for (int j = 0; j < 8; ++j) {             // issue 8 sequential row loads
            int k = k0 + j;
            tt[j] = __shfl(myt, k);
            vbuf[j] = make_float2(0.0f, 0.0f);
            if (tt[j] >= 0 && lane < 48)
                vbuf[j] = ((const float2*)(feats + (size_t)(a + k) * C_))[lane];
        }
#pragma unroll
        for (int j = 0; j < 8; ++j) {
            if (tt[j] != cur) {
                if (cur >= 0) flush_run(cur, ax, ay, lane, cnt, out);
                cur = tt[j]; ax = 0.0f; ay = 0.0f;
            }
            ax += vbuf[j].x; ay += vbuf[j].y;
        }
    }
    if (cur >= 0) flush_run(cur, ax, ay, lane, cnt, out);
}

extern "C" void kernel_launch(void* const* d_in, const int* in_sizes, int n_in,
                              void* d_out, int out_size, void* d_ws, size_t ws_size,
                              hipStream_t stream) {
    const float* feats  = (const float*)d_in[0];
    const int*   coords = (const int*)d_in[1];
    const float* vm     = (const float*)d_in[2];
    const float* intr   = (const float*)d_in[3];

    float* out     = (float*)d_out;                  // NVOX*C_ floats
    float* cnt_out = out + (size_t)NVOX * C_;        // NVOX floats

    char* ws = (char*)d_ws;
    // zero region (one 1.3MB memset): [unused 64B] | cnt | mask
    int*                cnt  = (int*)(ws + 64);              // 800,000 B
    unsigned long long* mask = (unsigned long long*)(ws + 800064); // 524,288 B -> ends 1,324,352
    int*  tgt = (int*)(ws + 1324416);                        // 614,400 B
    int*  occ = (int*)(ws + 4786816);                        // 33,554,432 B (mask-gated)

    (void)hipMemsetAsync(ws, 0, 1324352, stream);

    occ_kernel<<<NB1, 256, 0, stream>>>(coords, occ, mask, out);
    march_kernel<<<2400, 256, 0, stream>>>(vm, intr, mask, occ, tgt, cnt);
    scatter_kernel<<<NRAYS / CHUNK / 4, 256, 0, stream>>>(feats, tgt, cnt, out, cnt_out);
}

// Round 8
// 189.610 us; speedup vs baseline: 3.1822x; 1.0146x over previous
//
#include <hip/hip_runtime.h>
#include <hip/hip_bf16.h>
#include <climits>

#define B_ 2
#define V_ 4
#define H_ 120
#define W_ 160
#define C_ 96
#define NVOX 200000
#define GRID_ 128
#define NSTEPS 156
#define NRAYS (B_*V_*H_*W_)       // 153600
#define NB1 ((NVOX + 255) / 256)  // 782 blocks over voxels
#define CHUNK 64                  // rays per wave in scatter (was 32)
#define OUTQ2 ((NVOX * C_) / 4)   // 4,800,000 float4s: out rows
#define NTHREADS_MARCH (2400 * 256)

// NOTE (round-7 post-mortem): every kernel <47us (top-5 cutoff); ~38us is op
// overhead (fit: ~9us/op over rounds 5-7); march is the prime suspect: wave =
// 16 pixels, exits only when ALL resolve; ~9% miss rays => 78% of waves run
// the full 5-iteration march. This round: (1) exact per-ray t-window (slab)
// bounds the wave loop — ok[] kept so results identical; (2) 77.6MB out-zero
// moved occ->march tail (latency-bound kernel: stores ride idle BW);
// (3) scatter CHUNK 32->64 (fewer waves, fewer run-split flushes).

// ------- Kernel A: occ id grid + 64-bit occupancy bitmask -------------------
// occ NOT pre-initialized (mask gates all reads). Raw coords: the reference's
// per-batch shift is a provable no-op (integer s => floor(pw-s)=floor(pw)-s).
__global__ void occ_kernel(const int* __restrict__ coords,
                           int* __restrict__ occ,
                           unsigned long long* __restrict__ mask) {
    int i = blockIdx.x * blockDim.x + threadIdx.x;
    if (i >= NVOX) return;
    int b = coords[i * 4 + 0];
    int x = coords[i * 4 + 1];
    int y = coords[i * 4 + 2];
    int z = coords[i * 4 + 3];
    int idx = ((b * GRID_ + z) * GRID_ + y) * GRID_ + x;
    atomicMax(&occ[idx], i);        // last-dup wins == max ray id
    atomicOr(&mask[idx >> 6], 1ull << (idx & 63));
}

// -------- Kernel B: step-parallel march + wave cnt + d_out zero tail --------
// Wave = 16 consecutive pixels x 4 step-blocks of 8 steps. Slab t-window
// clips the outer loop to the union of the 16 rays' in-bounds intervals.
__global__ void march_kernel(const float* __restrict__ vm,
                             const float* __restrict__ intr,
                             const unsigned long long* __restrict__ mask,
                             const int* __restrict__ occ,
                             int* __restrict__ tgt,
                             int* __restrict__ cnt,
                             float* __restrict__ out) {
    int gt   = blockIdx.x * blockDim.x + threadIdx.x;
    int lane = threadIdx.x & 63;
    int p    = lane & 15;
    int sub  = lane >> 4;
    int r    = ((gt >> 6) << 4) + p;   // grid exactly covers NRAYS
    {
        int w = r % W_;
        int h = (r / W_) % H_;
        int v = (r / (W_ * H_)) % V_;
        int b = r / (W_ * H_ * V_);
        const float* M = vm + (size_t)(b * V_ + v) * 16;
        float fx = intr[0], fy = intr[1], cx = intr[2], cy = intr[3];
        float dx = ((float)w + 0.5f - cx) / fx;
        float dy = ((float)h + 0.5f - cy) / fy;
        // d = R * (dx, dy, 1); t = raw translation (no shift)
        float d0 = M[0] * dx + M[1] * dy + M[2];
        float d1 = M[4] * dx + M[5] * dy + M[6];
        float d2 = M[8] * dx + M[9] * dy + M[10];
        float t0 = M[3];
        float t1 = M[7];
        float t2 = M[11];
        // ---- slab t-window: exact in-bounds interval, widened +-1 step -----
        float i0 = 1.0f / d0, i1 = 1.0f / d1, i2 = 1.0f / d2;  // +-inf ok
        float a0 = (0.0f - t0) * i0, b0 = (128.0f - t0) * i0;
        float a1 = (0.0f - t1) * i1, b1 = (128.0f - t1) * i1;
        float a2 = (0.0f - t2) * i2, b2 = (128.0f - t2) * i2;
        float tlo = fmaxf(fmaxf(fminf(a0, b0), fminf(a1, b1)), fminf(a2, b2));
        float thi = fminf(fminf(fmaxf(a0, b0), fmaxf(a1, b1)), fmaxf(a2, b2));
        bool dead = !(tlo <= thi);                   // also catches NaN
        float slo = fmaxf((tlo - 2.0f) * 2.0f, 0.0f);            // clamp BEFORE
        float shi = fminf((thi - 2.0f) * 2.0f, (float)(NSTEPS - 1)); // int-cvt
        int st_lo = dead ? NSTEPS : max(0, (int)slo - 1);
        int st_hi = dead ? -1 : min(NSTEPS - 1, (int)shi + 1);
        // wave-wide window union (12 shuffles, once per wave)
        int wlo = st_lo, whi = st_hi;
#pragma unroll
        for (int m = 1; m < 64; m <<= 1) {
            wlo = min(wlo, __shfl_xor(wlo, m));
            whi = max(whi, __shfl_xor(whi, m));
        }
        const int vbase = b * GRID_ * GRID_ * GRID_;
        const int MISS = 0x7FFFFFFF;
        int beststep = MISS;
        for (int w0 = (wlo & ~31); w0 <= whi; w0 += 32) {
            int lin[8]; bool ok[8];
#pragma unroll
            for (int j = 0; j < 8; ++j) {
                int st = w0 + sub * 8 + j;
                float t = 2.0f + 0.5f * (float)st;
                float pwx = d0 * t + t0;
                float pwy = d1 * t + t1;
                float pwz = d2 * t + t2;
                int ix = (int)floorf(pwx);
                int iy = (int)floorf(pwy);
                int iz = (int)floorf(pwz);
                ok[j] = ((unsigned)ix < (unsigned)GRID_) &
                        ((unsigned)iy < (unsigned)GRID_) &
                        ((unsigned)iz < (unsigned)GRID_) & (st < NSTEPS);
                int cix = min(max(ix, 0), GRID_ - 1);
                int ciy = min(max(iy, 0), GRID_ - 1);
                int ciz = min(max(iz, 0), GRID_ - 1);
                lin[j] = vbase + (ciz << 14) + (ciy << 7) + cix;
            }
            unsigned long long u[8];
            bool same[8];
            same[0] = false;
#pragma unroll
            for (int j = 1; j < 8; ++j) same[j] = ((lin[j] >> 6) == (lin[j - 1] >> 6));
#pragma unroll
            for (int j = 0; j < 8; ++j)
                if (!same[j]) u[j] = mask[lin[j] >> 6];
#pragma unroll
            for (int j = 1; j < 8; ++j)
                if (same[j]) u[j] = u[j - 1];
            int local = MISS;
#pragma unroll
            for (int j = 0; j < 8; ++j) {
                int st = w0 + sub * 8 + j;
                if (ok[j] && ((u[j] >> (lin[j] & 63)) & 1ull)) local = min(local, st);
            }
            local = min(local, __shfl_xor(local, 16));
            local = min(local, __shfl_xor(local, 32));
            if (local != MISS) { beststep = local; break; }
        }
        // resolve first-hit id (only the 16 result lanes read occ)
        int res = -1;
        if (sub == 0) {
            if (beststep != MISS) {
                float t = 2.0f + 0.5f * (float)beststep;
                int ix = (int)floorf(d0 * t + t0);
                int iy = (int)floorf(d1 * t + t1);
                int iz = (int)floorf(d2 * t + t2);
                res = occ[vbase + (iz << 14) + (iy << 7) + ix];
            }
            tgt[r] = res;
        }
        // wave-aggregated histogram: one atomic per contiguous equal-target run
        bool active = (sub == 0) && (res >= 0);
        int prevres = __shfl_up(res, 1);
        bool head = active && (p == 0 || prevres != res);
        bool boundary = head || !active;
        unsigned long long bb = __ballot(boundary);
        if (head) {
            unsigned long long above = bb & ~((2ull << lane) - 1);  // boundaries > lane
            int next = above ? (__ffsll((long long)above) - 1) : 64;
            atomicAdd(&cnt[res], next - lane);                      // run length
        }
    }
    // ---- folded zero of the out-row region (76.8 MB): latency-bound kernel,
    // stores ride idle BW; consumed by scatter, 1 boundary downstream. -------
    float4 z4 = make_float4(0.f, 0.f, 0.f, 0.f);
    float4* o4 = (float4*)out;
    for (int i = gt; i < OUTQ2; i += NTHREADS_MARCH) o4[i] = z4;
}

// ---------------- run flush: pre-divided atomic accumulate ------------------
__device__ __forceinline__ void flush_run(int t, float ax, float ay, int lane,
                                          const int* __restrict__ cnt,
                                          float* __restrict__ out) {
    float denom = (float)cnt[t] + 0.0001f;   // same addr all lanes: broadcast
    if (lane < 48) {
        unsafeAtomicAdd(out + (size_t)t * C_ + 2 * lane,     ax / denom);
        unsafeAtomicAdd(out + (size_t)t * C_ + 2 * lane + 1, ay / denom);
    }
}

// ---------------- Kernel C: ray-order scatter (8-deep pipeline) -------------
// Wave = CHUNK=64 consecutive rays; lane<48 = channel pair. feats rows stream
// SEQUENTIALLY. Runs of equal tgt (image-space coherence) are summed in
// registers and flushed with ONE pair of atomic instructions per run,
// pre-divided by cnt[t]+1e-4 (cnt complete after march). Tail: cnt_out.
__global__ void scatter_kernel(const float* __restrict__ feats,
                               const int* __restrict__ tgt,
                               const int* __restrict__ cnt,
                               float* __restrict__ out,
                               float* __restrict__ cnt_out) {
    int gthread = blockIdx.x * blockDim.x + threadIdx.x;
    int lane = threadIdx.x & 63;
    for (int i = gthread; i < NVOX; i += NRAYS)      // total threads = NRAYS
        cnt_out[i] = (float)cnt[i];
    int wave = gthread >> 6;
    int a = wave * CHUNK;                 // grid sized exactly: a < NRAYS
    int myt = tgt[a + lane];              // 64 rays per wave
    float ax = 0.0f, ay = 0.0f;
    int cur = -1;
    for (int k0 = 0; k0 < CHUNK; k0 += 8) {
        float2 vbuf[8]; int tt[8];
#pragma unroll
        for (int j = 0; j < 8; ++j) {             // issue 8 sequential row loads
            int k = k0 + j;
            tt[j] = __shfl(myt, k);
            vbuf[j] = make_float2(0.0f, 0.0f);
            if (tt[j] >= 0 && lane < 48)
                vbuf[j] = ((const float2*)(feats + (size_t)(a + k) * C_))[lane];
        }
#pragma unroll
        for (int j = 0; j < 8; ++j) {
            if (tt[j] != cur) {
                if (cur >= 0) flush_run(cur, ax, ay, lane, cnt, out);
                cur = tt[j]; ax = 0.0f; ay = 0.0f;
            }
            ax += vbuf[j].x; ay += vbuf[j].y;
        }
    }
    if (cur >= 0) flush_run(cur, ax, ay, lane, cnt, out);
}

extern "C" void kernel_launch(void* const* d_in, const int* in_sizes, int n_in,
                              void* d_out, int out_size, void* d_ws, size_t ws_size,
                              hipStream_t stream) {
    const float* feats  = (const float*)d_in[0];
    const int*   coords = (const int*)d_in[1];
    const float* vm     = (const float*)d_in[2];
    const float* intr   = (const float*)d_in[3];

    float* out     = (float*)d_out;                  // NVOX*C_ floats
    float* cnt_out = out + (size_t)NVOX * C_;        // NVOX floats

    char* ws = (char*)d_ws;
    // zero region (one 1.3MB memset): [unused 64B] | cnt | mask
    int*                cnt  = (int*)(ws + 64);              // 800,000 B
    unsigned long long* mask = (unsigned long long*)(ws + 800064); // 524,288 B -> ends 1,324,352
    int*  tgt = (int*)(ws + 1324416);                        // 614,400 B
    int*  occ = (int*)(ws + 4786816);                        // 33,554,432 B (mask-gated)

    (void)hipMemsetAsync(ws, 0, 1324352, stream);

    occ_kernel<<<NB1, 256, 0, stream>>>(coords, occ, mask);
    march_kernel<<<2400, 256, 0, stream>>>(vm, intr, mask, occ, tgt, cnt, out);
    scatter_kernel<<<NRAYS / 256, 256, 0, stream>>>(feats, tgt, cnt, out, cnt_out);
}